// Round 9
// baseline (222.062 us; speedup 1.0000x reference)
//
#include <hip/hip_runtime.h>
#include <hip/hip_bf16.h>
#include <math.h>

#define SS 128
#define BB 32
#define VV 32000
#define EE 32
#define HH 16
#define KK 32                 // 2*HH = GEMM K
#define NROWS (SS*BB)         // 4096
#define NSL 16                // vocab slices per row-tile
#define VT 125                // 16-wide vocab tiles per slice (16*125*16 = 32000)

typedef __attribute__((ext_vector_type(4))) float f32x4;
typedef __attribute__((ext_vector_type(8))) short bf16x8;
typedef __attribute__((ext_vector_type(4))) short s16x4;

// DPP cross-lane within 16-lane rows (VALU pipe, no LDS).
// ctrl: quad_perm[1,0,3,2]=0xB1 (xor1), [2,3,0,1]=0x4E (xor2),
//       [3,2,1,0]=0x1B (xor3), ROW_HALF_MIRROR=0x141 (xor7),
//       ROW_MIRROR=0x140 (xor15).
#define DPPF(x, ctrl) __builtin_bit_cast(float, __builtin_amdgcn_update_dpp( \
    __builtin_bit_cast(int, (x)), __builtin_bit_cast(int, (x)), (ctrl), 0xF, 0xF, false))

// ------------------------------------------------------------------
// Prep: blocks 0..999 convert W_ho->bf16; blocks 1000..1511 do xproj.
// ------------------------------------------------------------------
__global__ __launch_bounds__(256) void k_prep(
    const float* __restrict__ Who, __hip_bfloat16* __restrict__ who_bf,
    const int* __restrict__ tok, const float* __restrict__ emb,
    const float* __restrict__ Wlr, const float* __restrict__ blr,
    const float* __restrict__ Wrl, const float* __restrict__ brl,
    float* __restrict__ xp) {
  if (blockIdx.x < 1000) {
    int i = blockIdx.x * 256 + threadIdx.x;      // < 256000 = VV*KK/4
    f32x4 v = ((const f32x4*)Who)[i];
    s16x4 o;
    #pragma unroll
    for (int q = 0; q < 4; ++q) {
      __hip_bfloat16 h = __float2bfloat16(v[q]);
      o[q] = *reinterpret_cast<short*>(&h);
    }
    ((s16x4*)who_bf)[i] = o;
  } else {
    int g = (blockIdx.x - 1000) * 256 + threadIdx.x;  // < 131072
    int dir = g >> 16;
    int rem = g & 65535;
    int t = rem >> 9;
    int b = (rem >> 4) & 31;
    int j = rem & 15;
    const float* W  = dir ? Wrl : Wlr;
    const float* bv = dir ? brl : blr;
    int tk = tok[t*BB + b];
    const float* er = emb + tk*EE;
    const float* wr = W + j*(EE+HH);
    float acc = bv[j];
    #pragma unroll
    for (int k = 0; k < EE; ++k) acc += er[k] * wr[k];
    xp[g] = acc;
  }
}

// ------------------------------------------------------------------
// RNN: DPP butterfly recurrence — all cross-lane on the VALU pipe.
// grid(8) x block(128): 2 waves/CU on 8 CUs, no LDS-pipe contention.
// Per step: 15 DPP gathers (xor1..15 via quad_perm/mirror compositions,
// chain depth <=3), pairwise FMA tree with weights wr[r]=W[j][j^r]
// (XOR mapping verified by R8), tanh, bf16 store.
// ------------------------------------------------------------------
__global__ __launch_bounds__(128) void k_rnn_fused(
    const float* __restrict__ xp,
    const float* __restrict__ h0lr, const float* __restrict__ h0rl,
    const float* __restrict__ Wlr, const float* __restrict__ Wrl,
    __hip_bfloat16* __restrict__ comb_bf) {
  int bid = blockIdx.x;
  int dir = bid >> 2;
  int b = (bid & 3) * 8 + (threadIdx.x >> 4);   // 0..31
  int j = threadIdx.x & 15;
  const float* W  = dir ? Wrl : Wlr;
  const float* h0 = dir ? h0rl : h0lr;
  float wr[HH];
  #pragma unroll
  for (int r = 0; r < HH; ++r) wr[r] = W[j*(EE+HH) + EE + (j ^ r)];
  const float* x = xp + dir * (SS*BB*HH);
  float h = h0[b*HH + j];
  if (dir == 0) comb_bf[0*(BB*KK) + b*KK + j] = __float2bfloat16(h);
  else          comb_bf[(SS-1)*(BB*KK) + b*KK + HH + j] = __float2bfloat16(h);
  int xoff  = dir ? ((SS-1)*BB*HH + b*HH + j) : (b*HH + j);
  int xstep = dir ? -(BB*HH) : (BB*HH);
  float xcur = x[xoff];
  for (int t = 1; t < SS; ++t) {
    float xnext = (t < SS-1) ? x[xoff + xstep] : 0.f;
    xoff += xstep;
    // 15 XOR gathers via DPP compositions
    float t1  = DPPF(h, 0xB1);      // j^1
    float t2  = DPPF(h, 0x4E);      // j^2
    float t3  = DPPF(h, 0x1B);      // j^3
    float t7  = DPPF(h, 0x141);     // j^7
    float t15 = DPPF(h, 0x140);     // j^15
    float t4  = DPPF(t7, 0x1B);     // j^4
    float t5  = DPPF(t7, 0x4E);     // j^5
    float t6  = DPPF(t7, 0xB1);     // j^6
    float t8  = DPPF(t15, 0x141);   // j^8
    float t12 = DPPF(t15, 0x1B);    // j^12
    float t13 = DPPF(t15, 0x4E);    // j^13
    float t14 = DPPF(t15, 0xB1);    // j^14
    float t9  = DPPF(t8, 0xB1);     // j^9
    float t10 = DPPF(t8, 0x4E);     // j^10
    float t11 = DPPF(t8, 0x1B);     // j^11
    float a0 = fmaf(wr[0], h,  xcur);
    a0 = fmaf(wr[4],  t4,  a0);
    a0 = fmaf(wr[8],  t8,  a0);
    a0 = fmaf(wr[12], t12, a0);
    float a1 = wr[1] * t1;
    a1 = fmaf(wr[5],  t5,  a1);
    a1 = fmaf(wr[9],  t9,  a1);
    a1 = fmaf(wr[13], t13, a1);
    float a2 = wr[2] * t2;
    a2 = fmaf(wr[6],  t6,  a2);
    a2 = fmaf(wr[10], t10, a2);
    a2 = fmaf(wr[14], t14, a2);
    float a3 = wr[3] * t3;
    a3 = fmaf(wr[7],  t7,  a3);
    a3 = fmaf(wr[11], t11, a3);
    a3 = fmaf(wr[15], t15, a3);
    float acc = (a0 + a1) + (a2 + a3);
    float e = __expf(2.f * acc);
    h = 1.f - 2.f / (e + 1.f);          // tanh(acc)
    int ci = dir ? ((SS-1-t)*(BB*KK) + b*KK + HH + j)
                 : (t*(BB*KK) + b*KK + j);
    comb_bf[ci] = __float2bfloat16(h);
    xcur = xnext;
  }
}

// ------------------------------------------------------------------
// Sum-exp: 4096 waves, XCD-swizzled (each XCD owns a contiguous
// 512-row band). wave = (row-tile rt, slice sl).
// ------------------------------------------------------------------
__global__ __launch_bounds__(256) void k_sumexp(
    const __hip_bfloat16* __restrict__ cb, const __hip_bfloat16* __restrict__ wb,
    const float* __restrict__ bho, float* __restrict__ part) {
  int wg = ((blockIdx.x & 7) << 7) | (blockIdx.x >> 3);  // bijective, 1024 blocks
  int w = wg * 4 + (threadIdx.x >> 6);
  int lane = threadIdx.x & 63;
  int rt = w >> 4;              // 0..255
  int sl = w & 15;              // 0..15
  int v0 = sl * (VT*16);
  int g = lane >> 4, c = lane & 15;
  bf16x8 bfr = *(const bf16x8*)(cb + (size_t)(rt*16 + c)*KK + g*8);
  float s = 0.f;
  for (int t = 0; t < VT; ++t) {
    int v = v0 + t*16;
    bf16x8 af = *(const bf16x8*)(wb + (size_t)(v + c)*KK + g*8);
    f32x4 bh = *(const f32x4*)(bho + v + g*4);
    f32x4 d = __builtin_amdgcn_mfma_f32_16x16x32_bf16(af, bfr, bh, 0, 0, 0);
    s += __expf(d[0]) + __expf(d[1]) + __expf(d[2]) + __expf(d[3]);
  }
  s += __shfl_xor(s, 16);
  s += __shfl_xor(s, 32);
  if (lane < 16)
    part[(size_t)(rt*16 + lane)*NSL + sl] = s;
}

// ------------------------------------------------------------------
// Write: direct 64B-segment stores, XCD-swizzled row bands.
// ------------------------------------------------------------------
__global__ __launch_bounds__(256) void k_write(
    const __hip_bfloat16* __restrict__ cb, const __hip_bfloat16* __restrict__ wb,
    const float* __restrict__ bho, const float* __restrict__ part,
    float* __restrict__ out) {
  int wg = ((blockIdx.x & 7) << 7) | (blockIdx.x >> 3);  // bijective, 1024 blocks
  int w = wg * 4 + (threadIdx.x >> 6);
  int lane = threadIdx.x & 63;
  int rt = w >> 4;
  int sl = w & 15;
  int v0 = sl * (VT*16);
  int g = lane >> 4, c = lane & 15;
  size_t row = rt*16 + c;
  const f32x4* pp = (const f32x4*)(part + row*NSL);
  f32x4 p0 = pp[0], p1 = pp[1], p2 = pp[2], p3 = pp[3];
  float s = (p0[0]+p0[1]+p0[2]+p0[3]) + (p1[0]+p1[1]+p1[2]+p1[3])
          + (p2[0]+p2[1]+p2[2]+p2[3]) + (p3[0]+p3[1]+p3[2]+p3[3]);
  float Lr = logf(s);
  bf16x8 bfr = *(const bf16x8*)(cb + row*KK + g*8);
  for (int t = 0; t < VT; ++t) {
    int v = v0 + t*16;
    bf16x8 af = *(const bf16x8*)(wb + (size_t)(v + c)*KK + g*8);
    f32x4 bh = *(const f32x4*)(bho + v + g*4);
    f32x4 cin = bh - Lr;
    f32x4 d = __builtin_amdgcn_mfma_f32_16x16x32_bf16(af, bfr, cin, 0, 0, 0);
    *(f32x4*)(out + row*VV + v + g*4) = d;
  }
}

// ------------------------------------------------------------------
extern "C" void kernel_launch(void* const* d_in, const int* in_sizes, int n_in,
                              void* d_out, int out_size, void* d_ws, size_t ws_size,
                              hipStream_t stream) {
  const int*   tok  = (const int*)d_in[0];
  const float* h0lr = (const float*)d_in[1];
  const float* h0rl = (const float*)d_in[2];
  const float* emb  = (const float*)d_in[3];
  const float* Wlr  = (const float*)d_in[4];
  const float* blr  = (const float*)d_in[5];
  const float* Wrl  = (const float*)d_in[6];
  const float* brl  = (const float*)d_in[7];
  const float* Who  = (const float*)d_in[8];
  const float* bho  = (const float*)d_in[9];
  float* out = (float*)d_out;
  float* ws  = (float*)d_ws;

  float* xp   = ws;                                           // 131072 floats
  float* part = ws + 131072;                                  // 4096*16 = 65536 floats
  __hip_bfloat16* comb_bf = (__hip_bfloat16*)(ws + 196608);   // 131072 bf16
  __hip_bfloat16* who_bf  = (__hip_bfloat16*)(ws + 262144);   // 1024000 bf16

  hipLaunchKernelGGL(k_prep, dim3(1512), dim3(256), 0, stream,
                     Who, who_bf, tok, emb, Wlr, blr, Wrl, brl, xp);
  hipLaunchKernelGGL(k_rnn_fused, dim3(8), dim3(128), 0, stream,
                     xp, h0lr, h0rl, Wlr, Wrl, comb_bf);
  hipLaunchKernelGGL(k_sumexp, dim3(1024), dim3(256), 0, stream,
                     comb_bf, who_bf, bho, part);
  hipLaunchKernelGGL(k_write, dim3(1024), dim3(256), 0, stream,
                     comb_bf, who_bf, bho, part, out);
}

// Round 10
// 214.192 us; speedup vs baseline: 1.0367x; 1.0367x over previous
//
#include <hip/hip_runtime.h>
#include <hip/hip_bf16.h>
#include <math.h>

#define SS 128
#define BB 32
#define VV 32000
#define EE 32
#define HH 16
#define KK 32                 // 2*HH = GEMM K
#define NROWS (SS*BB)         // 4096
#define NSL 16                // vocab slices per row-tile
#define VT 125                // 16-wide vocab tiles per slice (16*125*16 = 32000)
#define NPRE 8                // rnn x-prefetch depth (reg ring)

typedef __attribute__((ext_vector_type(4))) float f32x4;
typedef __attribute__((ext_vector_type(8))) short bf16x8;
typedef __attribute__((ext_vector_type(4))) short s16x4;

// DPP cross-lane within 16-lane rows (VALU pipe, no LDS).
#define DPPF(x, ctrl) __builtin_bit_cast(float, __builtin_amdgcn_update_dpp( \
    __builtin_bit_cast(int, (x)), __builtin_bit_cast(int, (x)), (ctrl), 0xF, 0xF, false))

// ------------------------------------------------------------------
// Prep: blocks 0..999 convert W_ho->bf16; blocks 1000..1511 do xproj.
// ------------------------------------------------------------------
__global__ __launch_bounds__(256) void k_prep(
    const float* __restrict__ Who, __hip_bfloat16* __restrict__ who_bf,
    const int* __restrict__ tok, const float* __restrict__ emb,
    const float* __restrict__ Wlr, const float* __restrict__ blr,
    const float* __restrict__ Wrl, const float* __restrict__ brl,
    float* __restrict__ xp) {
  if (blockIdx.x < 1000) {
    int i = blockIdx.x * 256 + threadIdx.x;      // < 256000 = VV*KK/4
    f32x4 v = ((const f32x4*)Who)[i];
    s16x4 o;
    #pragma unroll
    for (int q = 0; q < 4; ++q) {
      __hip_bfloat16 h = __float2bfloat16(v[q]);
      o[q] = *reinterpret_cast<short*>(&h);
    }
    ((s16x4*)who_bf)[i] = o;
  } else {
    int g = (blockIdx.x - 1000) * 256 + threadIdx.x;  // < 131072
    int dir = g >> 16;
    int rem = g & 65535;
    int t = rem >> 9;
    int b = (rem >> 4) & 31;
    int j = rem & 15;
    const float* W  = dir ? Wrl : Wlr;
    const float* bv = dir ? brl : blr;
    int tk = tok[t*BB + b];
    const float* er = emb + tk*EE;
    const float* wr = W + j*(EE+HH);
    float acc = bv[j];
    #pragma unroll
    for (int k = 0; k < EE; ++k) acc += er[k] * wr[k];
    xp[g] = acc;
  }
}

// ------------------------------------------------------------------
// RNN: DPP butterfly + 8-deep register-ring x prefetch. The per-step
// serial chain (DPP gathers, FMA tree, tanh) is ~120 cy; the x load
// for step t+8 is issued at step t, so ~1200 cy of load latency is
// in flight — global-load latency fully hidden.
// ------------------------------------------------------------------
__global__ __launch_bounds__(128) void k_rnn_fused(
    const float* __restrict__ xp,
    const float* __restrict__ h0lr, const float* __restrict__ h0rl,
    const float* __restrict__ Wlr, const float* __restrict__ Wrl,
    __hip_bfloat16* __restrict__ comb_bf) {
  int bid = blockIdx.x;
  int dir = bid >> 2;
  int b = (bid & 3) * 8 + (threadIdx.x >> 4);   // 0..31
  int j = threadIdx.x & 15;
  const float* W  = dir ? Wrl : Wlr;
  const float* h0 = dir ? h0rl : h0lr;
  float wr[HH];
  #pragma unroll
  for (int r = 0; r < HH; ++r) wr[r] = W[j*(EE+HH) + EE + (j ^ r)];
  const float* x = xp + dir * (SS*BB*HH);
  int u = b*HH + j;
  float h = h0[u];
  if (dir == 0) comb_bf[0*(BB*KK) + b*KK + j] = __float2bfloat16(h);
  else          comb_bf[(SS-1)*(BB*KK) + b*KK + HH + j] = __float2bfloat16(h);
  // ring preload: xbuf[i] holds x consumed at step tc+i
  float xbuf[NPRE];
  #pragma unroll
  for (int p = 0; p < NPRE; ++p) {
    int tt = 1 + p;
    int off = dir ? (SS-tt)*(BB*HH) + u : (tt-1)*(BB*HH) + u;
    xbuf[p] = x[off];
  }
  for (int tc = 1; tc < SS; tc += NPRE) {
    #pragma unroll
    for (int i = 0; i < NPRE; ++i) {
      int t = tc + i;
      if (t < SS) {
        float xv = xbuf[i];
        // prefetch for step t+NPRE (dummy in-bounds addr when past end)
        int tp = t + NPRE;
        int offp = (tp < SS) ? (dir ? (SS-tp)*(BB*HH) + u : (tp-1)*(BB*HH) + u) : u;
        xbuf[i] = x[offp];
        // 15 XOR gathers via DPP compositions
        float t1  = DPPF(h, 0xB1);      // j^1
        float t2  = DPPF(h, 0x4E);      // j^2
        float t3  = DPPF(h, 0x1B);      // j^3
        float t7  = DPPF(h, 0x141);     // j^7
        float t15 = DPPF(h, 0x140);     // j^15
        float t4  = DPPF(t7, 0x1B);     // j^4
        float t5  = DPPF(t7, 0x4E);     // j^5
        float t6  = DPPF(t7, 0xB1);     // j^6
        float t8  = DPPF(t15, 0x141);   // j^8
        float t12 = DPPF(t15, 0x1B);    // j^12
        float t13 = DPPF(t15, 0x4E);    // j^13
        float t14 = DPPF(t15, 0xB1);    // j^14
        float t9  = DPPF(t8, 0xB1);     // j^9
        float t10 = DPPF(t8, 0x4E);     // j^10
        float t11 = DPPF(t8, 0x1B);     // j^11
        float a0 = fmaf(wr[0], h,  xv);
        a0 = fmaf(wr[4],  t4,  a0);
        a0 = fmaf(wr[8],  t8,  a0);
        a0 = fmaf(wr[12], t12, a0);
        float a1 = wr[1] * t1;
        a1 = fmaf(wr[5],  t5,  a1);
        a1 = fmaf(wr[9],  t9,  a1);
        a1 = fmaf(wr[13], t13, a1);
        float a2 = wr[2] * t2;
        a2 = fmaf(wr[6],  t6,  a2);
        a2 = fmaf(wr[10], t10, a2);
        a2 = fmaf(wr[14], t14, a2);
        float a3 = wr[3] * t3;
        a3 = fmaf(wr[7],  t7,  a3);
        a3 = fmaf(wr[11], t11, a3);
        a3 = fmaf(wr[15], t15, a3);
        float acc = (a0 + a1) + (a2 + a3);
        float e = __expf(2.f * acc);
        h = fmaf(-2.f, __builtin_amdgcn_rcpf(e + 1.f), 1.f);   // tanh(acc)
        int ci = dir ? ((SS-1-t)*(BB*KK) + b*KK + HH + j)
                     : (t*(BB*KK) + b*KK + j);
        comb_bf[ci] = __float2bfloat16(h);
      }
    }
  }
}

// ------------------------------------------------------------------
// Sum-exp: 4096 waves, XCD-swizzled. wave = (row-tile rt, slice sl).
// ------------------------------------------------------------------
__global__ __launch_bounds__(256) void k_sumexp(
    const __hip_bfloat16* __restrict__ cb, const __hip_bfloat16* __restrict__ wb,
    const float* __restrict__ bho, float* __restrict__ part) {
  int wg = ((blockIdx.x & 7) << 7) | (blockIdx.x >> 3);  // bijective, 1024 blocks
  int w = wg * 4 + (threadIdx.x >> 6);
  int lane = threadIdx.x & 63;
  int rt = w >> 4;              // 0..255
  int sl = w & 15;              // 0..15
  int v0 = sl * (VT*16);
  int g = lane >> 4, c = lane & 15;
  bf16x8 bfr = *(const bf16x8*)(cb + (size_t)(rt*16 + c)*KK + g*8);
  float s = 0.f;
  for (int t = 0; t < VT; ++t) {
    int v = v0 + t*16;
    bf16x8 af = *(const bf16x8*)(wb + (size_t)(v + c)*KK + g*8);
    f32x4 bh = *(const f32x4*)(bho + v + g*4);
    f32x4 d = __builtin_amdgcn_mfma_f32_16x16x32_bf16(af, bfr, bh, 0, 0, 0);
    s += __expf(d[0]) + __expf(d[1]) + __expf(d[2]) + __expf(d[3]);
  }
  s += __shfl_xor(s, 16);
  s += __shfl_xor(s, 32);
  if (lane < 16)
    part[(size_t)(rt*16 + lane)*NSL + sl] = s;
}

// ------------------------------------------------------------------
// Write: direct 64B-segment stores, XCD-swizzled row bands.
// ------------------------------------------------------------------
__global__ __launch_bounds__(256) void k_write(
    const __hip_bfloat16* __restrict__ cb, const __hip_bfloat16* __restrict__ wb,
    const float* __restrict__ bho, const float* __restrict__ part,
    float* __restrict__ out) {
  int wg = ((blockIdx.x & 7) << 7) | (blockIdx.x >> 3);  // bijective, 1024 blocks
  int w = wg * 4 + (threadIdx.x >> 6);
  int lane = threadIdx.x & 63;
  int rt = w >> 4;
  int sl = w & 15;
  int v0 = sl * (VT*16);
  int g = lane >> 4, c = lane & 15;
  size_t row = rt*16 + c;
  const f32x4* pp = (const f32x4*)(part + row*NSL);
  f32x4 p0 = pp[0], p1 = pp[1], p2 = pp[2], p3 = pp[3];
  float s = (p0[0]+p0[1]+p0[2]+p0[3]) + (p1[0]+p1[1]+p1[2]+p1[3])
          + (p2[0]+p2[1]+p2[2]+p2[3]) + (p3[0]+p3[1]+p3[2]+p3[3]);
  float Lr = logf(s);
  bf16x8 bfr = *(const bf16x8*)(cb + row*KK + g*8);
  for (int t = 0; t < VT; ++t) {
    int v = v0 + t*16;
    bf16x8 af = *(const bf16x8*)(wb + (size_t)(v + c)*KK + g*8);
    f32x4 bh = *(const f32x4*)(bho + v + g*4);
    f32x4 cin = bh - Lr;
    f32x4 d = __builtin_amdgcn_mfma_f32_16x16x32_bf16(af, bfr, cin, 0, 0, 0);
    *(f32x4*)(out + row*VV + v + g*4) = d;
  }
}

// ------------------------------------------------------------------
extern "C" void kernel_launch(void* const* d_in, const int* in_sizes, int n_in,
                              void* d_out, int out_size, void* d_ws, size_t ws_size,
                              hipStream_t stream) {
  const int*   tok  = (const int*)d_in[0];
  const float* h0lr = (const float*)d_in[1];
  const float* h0rl = (const float*)d_in[2];
  const float* emb  = (const float*)d_in[3];
  const float* Wlr  = (const float*)d_in[4];
  const float* blr  = (const float*)d_in[5];
  const float* Wrl  = (const float*)d_in[6];
  const float* brl  = (const float*)d_in[7];
  const float* Who  = (const float*)d_in[8];
  const float* bho  = (const float*)d_in[9];
  float* out = (float*)d_out;
  float* ws  = (float*)d_ws;

  float* xp   = ws;                                           // 131072 floats
  float* part = ws + 131072;                                  // 4096*16 = 65536 floats
  __hip_bfloat16* comb_bf = (__hip_bfloat16*)(ws + 196608);   // 131072 bf16
  __hip_bfloat16* who_bf  = (__hip_bfloat16*)(ws + 262144);   // 1024000 bf16

  hipLaunchKernelGGL(k_prep, dim3(1512), dim3(256), 0, stream,
                     Who, who_bf, tok, emb, Wlr, blr, Wrl, brl, xp);
  hipLaunchKernelGGL(k_rnn_fused, dim3(8), dim3(128), 0, stream,
                     xp, h0lr, h0rl, Wlr, Wrl, comb_bf);
  hipLaunchKernelGGL(k_sumexp, dim3(1024), dim3(256), 0, stream,
                     comb_bf, who_bf, bho, part);
  hipLaunchKernelGGL(k_write, dim3(1024), dim3(256), 0, stream,
                     comb_bf, who_bf, bho, part, out);
}